// Round 4
// baseline (662.388 us; speedup 1.0000x reference)
//
#include <hip/hip_runtime.h>
#include <hip/hip_fp16.h>

#define NEG_SLOPE 0.2f

typedef _Float16 half8 __attribute__((ext_vector_type(8)));
typedef float float4v __attribute__((ext_vector_type(4)));

// ---------------- Kernel: node prep layer 1 ----------------
__global__ void k_node1(const float* __restrict__ x, const int* __restrict__ type_ids,
                        const float* __restrict__ type_emb, const float* __restrict__ W1,
                        const float* __restrict__ a_src1, const float* __restrict__ a_dst1,
                        __half2* __restrict__ h1h, float* __restrict__ als1, float* __restrict__ ald1,
                        int N)
{
    int node = blockIdx.x * 4 + (threadIdx.x >> 6);
    int j = threadIdx.x & 63;
    if (node >= N) return;

    float xin[21];
#pragma unroll
    for (int k = 0; k < 5; k++) xin[k] = x[node * 5 + k];
    int t = type_ids[node];
#pragma unroll
    for (int k = 0; k < 16; k++) xin[5 + k] = type_emb[t * 16 + k];

    float h = 0.f;
#pragma unroll
    for (int k = 0; k < 21; k++) h += xin[k] * W1[k * 64 + j];

    float hn = __shfl_xor(h, 1);
    if ((j & 1) == 0)
        h1h[node * 32 + (j >> 1)] = __floats2half2_rn(h, hn);

    int head = j >> 5, lane = j & 31;
    float ps = h * a_src1[head * 32 + lane];
    float pd = h * a_dst1[head * 32 + lane];
#pragma unroll
    for (int m = 16; m >= 1; m >>= 1) { ps += __shfl_xor(ps, m); pd += __shfl_xor(pd, m); }
    if (lane == 0) { als1[node * 2 + head] = ps; ald1[node * 2 + head] = pd; }
}

// ---------------- CSR build v2: global counting sort ----------------
__global__ void k_deg(const int* __restrict__ ei, int* __restrict__ deg, int E)
{
    int tid = blockIdx.x * blockDim.x + threadIdx.x;
    int stride = gridDim.x * blockDim.x;
    int n4 = E >> 2;
    const int4* d4 = (const int4*)(ei + (size_t)E);
    for (int c = tid; c < n4; c += stride) {
        int4 d = d4[c];
        atomicAdd(&deg[d.x], 1);
        atomicAdd(&deg[d.y], 1);
        atomicAdd(&deg[d.z], 1);
        atomicAdd(&deg[d.w], 1);
    }
    for (int e = (n4 << 2) + tid; e < E; e += stride)
        atomicAdd(&deg[ei[(size_t)E + e]], 1);
}

__global__ void k_scan1(const int* __restrict__ deg, int* __restrict__ btot, int N)
{
    __shared__ int sm[256];
    int t = threadIdx.x;
    int n = blockIdx.x * 256 + t;
    sm[t] = (n < N) ? deg[n] : 0;
    __syncthreads();
    for (int off = 128; off; off >>= 1) {
        if (t < off) sm[t] += sm[t + off];
        __syncthreads();
    }
    if (t == 0) btot[blockIdx.x] = sm[0];
}

__global__ void k_scan2(const int* __restrict__ btot, int* __restrict__ bbase, int nb)
{
    __shared__ int sm[512];
    int t = threadIdx.x;
    int carry = 0;
    for (int base = 0; base < nb; base += 512) {
        int i = base + t;
        int v = (i < nb) ? btot[i] : 0;
        sm[t] = v;
        __syncthreads();
        for (int off = 1; off < 512; off <<= 1) {
            int u = (t >= off) ? sm[t - off] : 0;
            __syncthreads();
            sm[t] += u;
            __syncthreads();
        }
        if (i < nb) bbase[i] = carry + sm[t] - v;
        carry += sm[511];
        __syncthreads();
    }
}

__global__ void k_scan3(const int* __restrict__ deg, const int* __restrict__ bbase,
                        int* __restrict__ rs, int* __restrict__ cur, int N)
{
    __shared__ int sm[256];
    int t = threadIdx.x;
    int n = blockIdx.x * 256 + t;
    int v = (n < N) ? deg[n] : 0;
    sm[t] = v;
    __syncthreads();
    for (int off = 1; off < 256; off <<= 1) {
        int u = (t >= off) ? sm[t - off] : 0;
        __syncthreads();
        sm[t] += u;
        __syncthreads();
    }
    if (n < N) {
        int r = bbase[blockIdx.x] + sm[t] - v;
        rs[n] = r;
        cur[n] = r;
    }
}

__global__ void k_scatter(const int* __restrict__ ei, int* __restrict__ cur,
                          int* __restrict__ ssrc, int E)
{
    int tid = blockIdx.x * blockDim.x + threadIdx.x;
    int stride = gridDim.x * blockDim.x;
    int n4 = E >> 2;
    const int4* s4 = (const int4*)ei;
    const int4* d4 = (const int4*)(ei + (size_t)E);
    for (int c = tid; c < n4; c += stride) {
        int4 s = s4[c];
        int4 d = d4[c];
        ssrc[atomicAdd(&cur[d.x], 1)] = s.x;
        ssrc[atomicAdd(&cur[d.y], 1)] = s.y;
        ssrc[atomicAdd(&cur[d.z], 1)] = s.z;
        ssrc[atomicAdd(&cur[d.w], 1)] = s.w;
    }
    for (int e = (n4 << 2) + tid; e < E; e += stride)
        ssrc[atomicAdd(&cur[ei[(size_t)E + e]], 1)] = ei[e];
}

// ---------------- Gather layer 1: 16 lanes/node (2x8 halves), 4 nodes/wave, fp32 acc ----------------
__global__ void k_gather1(const int* __restrict__ rs, const int* __restrict__ cur,
                          const int* __restrict__ ssrc, const float4* __restrict__ h4,
                          const float* __restrict__ als1, const float* __restrict__ ald1,
                          const float* __restrict__ b1, float4* __restrict__ h2h4, int N)
{
    int t = threadIdx.x;
    int l = t & 63;
    int q = l & 15;          // lane within node group
    int i = q & 7;           // channel octet owner (channels 8i..8i+7)
    int hlf = q >> 3;        // slot-half
    int grpbase = l & 48;
    int head = i >> 2;

    int node = blockIdx.x * 16 + (t >> 4);
    bool live = node < N;
    int node_c = live ? node : (N - 1);

    int beg = rs[node_c];
    int cnt = live ? (cur[node_c] - beg) : 0;

    float ad0 = ald1[node_c * 2 + 0];
    float ad1 = ald1[node_c * 2 + 1];
    float ad = head ? ad1 : ad0;

    // wave-wide max degree (cnt uniform within each 16-lane group)
    int mc = cnt;
    mc = max(mc, __shfl_xor(mc, 16));
    mc = max(mc, __shfl_xor(mc, 32));

    float acc[8];
#pragma unroll
    for (int k = 0; k < 8; k++) acc[k] = 0.f;
    float wsum = 0.f;

    for (int b = 0; b < mc; b += 16) {
        // phase 1: lane q owns slot b+q of its group's list
        int slot = b + q;
        bool valid = slot < cnt;
        int idx = valid ? (beg + slot) : 0;
        int s = ssrc[idx];
        if (!valid) s = node_c;
        float2 al = *(const float2*)(als1 + (size_t)s * 2);
        float lg0 = al.x + ad0; lg0 = (lg0 >= 0.f) ? lg0 : NEG_SLOPE * lg0;
        float lg1 = al.y + ad1; lg1 = (lg1 >= 0.f) ? lg1 : NEG_SLOPE * lg1;
        float w0 = valid ? __expf(lg0) : 0.f;
        float w1 = valid ? __expf(lg1) : 0.f;
        __half2 wp = __floats2half2_rn(w0, w1);
        unsigned wpi = *(unsigned*)&wp;

        // phase 2: 8 rounds; each half processes its 8 slots (2 edges/node/round)
#pragma unroll
        for (int r = 0; r < 8; r++) {
            int srcl = grpbase + hlf * 8 + r;
            int sr = __shfl(s, srcl);
            unsigned wri = __shfl(wpi, srcl);
            __half2 wh = *(__half2*)&wri;
            float w = head ? __high2float(wh) : __low2float(wh);
            float4 rv = h4[(size_t)sr * 8 + i];
            const __half* hp = (const __half*)&rv;
#pragma unroll
            for (int k = 0; k < 8; k++)
                acc[k] = fmaf(w, __half2float(hp[k]), acc[k]);
            wsum += w;
        }
    }

    // merge the two halves
#pragma unroll
    for (int k = 0; k < 8; k++) acc[k] += __shfl_xor(acc[k], 8);
    wsum += __shfl_xor(wsum, 8);

    // self loop
    {
        float lg = als1[node_c * 2 + head] + ad;
        lg = (lg >= 0.f) ? lg : NEG_SLOPE * lg;
        float w = __expf(lg);
        float4 rv = h4[(size_t)node_c * 8 + i];
        const __half* hp = (const __half*)&rv;
#pragma unroll
        for (int k = 0; k < 8; k++)
            acc[k] = fmaf(w, __half2float(hp[k]), acc[k]);
        wsum += w;
    }

    float inv = 1.f / (wsum + 1e-16f);
    if (live && hlf == 0) {
        union { float4 f4; __half2 h2[4]; } u;
#pragma unroll
        for (int c = 0; c < 4; c++) {
            float v0 = fmaxf(acc[2*c]   * inv + b1[i * 8 + 2*c],     0.f);
            float v1 = fmaxf(acc[2*c+1] * inv + b1[i * 8 + 2*c + 1], 0.f);
            u.h2[c] = __floats2half2_rn(v0, v1);
        }
        h2h4[(size_t)node * 8 + i] = u.f4;
    }
}

// ---------------- MFMA projection: h3 = h2 @ W2 (fp16 in, fp32 acc) + logits ----------------
__global__ __launch_bounds__(256) void k_node2m(
        const _Float16* __restrict__ h2h, const float* __restrict__ W2,
        const float* __restrict__ a_src2, const float* __restrict__ a_dst2,
        _Float16* __restrict__ h3h, float* __restrict__ als2, float* __restrict__ ald2, int N)
{
    __shared__ _Float16 w2t[64][72];
    __shared__ float h3t[4][16][65];
    int t = threadIdx.x;
    for (int e = t; e < 4096; e += 256) {
        int k = e >> 6, n = e & 63;
        w2t[n][k] = (_Float16)W2[e];
    }
    __syncthreads();

    int w = t >> 6, l = t & 63;
    int l15 = l & 15, quad = l >> 4;
    int nodebase = blockIdx.x * 64 + w * 16;

    int arow = nodebase + l15;
    if (arow >= N) arow = N - 1;
    const half8* ap = (const half8*)(h2h + (size_t)arow * 64 + quad * 8);
    half8 a0 = ap[0];
    half8 a1 = ap[4];
    float4v accs[4];
#pragma unroll
    for (int nt = 0; nt < 4; nt++) {
        half8 b0 = *(const half8*)(&w2t[nt * 16 + l15][quad * 8]);
        half8 b1 = *(const half8*)(&w2t[nt * 16 + l15][32 + quad * 8]);
        float4v c = {0.f, 0.f, 0.f, 0.f};
        c = __builtin_amdgcn_mfma_f32_16x16x32_f16(a0, b0, c, 0, 0, 0);
        c = __builtin_amdgcn_mfma_f32_16x16x32_f16(a1, b1, c, 0, 0, 0);
        accs[nt] = c;
    }
#pragma unroll
    for (int nt = 0; nt < 4; nt++)
#pragma unroll
        for (int r = 0; r < 4; r++)
            h3t[w][quad * 4 + r][nt * 16 + l15] = accs[nt][r];
    __syncthreads();

    int m = l >> 2, part = l & 3;
    int g = blockIdx.x * 64 + w * 16 + m;
    float ps = 0.f, pd = 0.f;
    union { float4 f4[2]; _Float16 h[16]; } u;
#pragma unroll
    for (int c = 0; c < 16; c++) {
        float v = h3t[w][m][part * 16 + c];
        ps += v * a_src2[part * 16 + c];
        pd += v * a_dst2[part * 16 + c];
        u.h[c] = (_Float16)v;
    }
    if (g < N) {
        float4* dst = (float4*)(h3h + (size_t)g * 64) + part * 2;
        dst[0] = u.f4[0];
        dst[1] = u.f4[1];
    }
    ps += __shfl_xor(ps, 1); ps += __shfl_xor(ps, 2);
    pd += __shfl_xor(pd, 1); pd += __shfl_xor(pd, 2);
    if (part == 0 && g < N) { als2[g] = ps; ald2[g] = pd; }
}

// ---------------- Gather layer 2: 16 lanes/node, 4 nodes/wave + LayerNorm ----------------
__global__ void k_gather2(const int* __restrict__ rs, const int* __restrict__ cur,
                          const int* __restrict__ ssrc, const float4* __restrict__ h4,
                          const float* __restrict__ als2, const float* __restrict__ ald2,
                          const float* __restrict__ b2, const float* __restrict__ gamma,
                          const float* __restrict__ beta, float* __restrict__ out, int N)
{
    int t = threadIdx.x;
    int l = t & 63;
    int q = l & 15;
    int i = q & 7;
    int hlf = q >> 3;
    int grpbase = l & 48;

    int node = blockIdx.x * 16 + (t >> 4);
    bool live = node < N;
    int node_c = live ? node : (N - 1);

    int beg = rs[node_c];
    int cnt = live ? (cur[node_c] - beg) : 0;
    float ad = ald2[node_c];

    int mc = cnt;
    mc = max(mc, __shfl_xor(mc, 16));
    mc = max(mc, __shfl_xor(mc, 32));

    float acc[8];
#pragma unroll
    for (int k = 0; k < 8; k++) acc[k] = 0.f;
    float wsum = 0.f;

    for (int b = 0; b < mc; b += 16) {
        int slot = b + q;
        bool valid = slot < cnt;
        int idx = valid ? (beg + slot) : 0;
        int s = ssrc[idx];
        if (!valid) s = node_c;
        float lg = als2[s] + ad;
        lg = (lg >= 0.f) ? lg : NEG_SLOPE * lg;
        float w = valid ? __expf(lg) : 0.f;

#pragma unroll
        for (int r = 0; r < 8; r++) {
            int srcl = grpbase + hlf * 8 + r;
            int sr = __shfl(s, srcl);
            float wr = __shfl(w, srcl);
            float4 rv = h4[(size_t)sr * 8 + i];
            const __half* hp = (const __half*)&rv;
#pragma unroll
            for (int k = 0; k < 8; k++)
                acc[k] = fmaf(wr, __half2float(hp[k]), acc[k]);
            wsum += wr;
        }
    }

    // merge halves
#pragma unroll
    for (int k = 0; k < 8; k++) acc[k] += __shfl_xor(acc[k], 8);
    wsum += __shfl_xor(wsum, 8);

    // self loop
    {
        float lg = als2[node_c] + ad;
        lg = (lg >= 0.f) ? lg : NEG_SLOPE * lg;
        float w = __expf(lg);
        float4 rv = h4[(size_t)node_c * 8 + i];
        const __half* hp = (const __half*)&rv;
#pragma unroll
        for (int k = 0; k < 8; k++)
            acc[k] = fmaf(w, __half2float(hp[k]), acc[k]);
        wsum += w;
    }

    float inv = 1.f / (wsum + 1e-16f);
    float o[8];
    float s = 0.f;
#pragma unroll
    for (int k = 0; k < 8; k++) { o[k] = acc[k] * inv + b2[i * 8 + k]; s += o[k]; }
    s += __shfl_xor(s, 1); s += __shfl_xor(s, 2); s += __shfl_xor(s, 4);
    float mu = s * (1.f / 64.f);
    float v = 0.f;
#pragma unroll
    for (int k = 0; k < 8; k++) { float d = o[k] - mu; v += d * d; }
    v += __shfl_xor(v, 1); v += __shfl_xor(v, 2); v += __shfl_xor(v, 4);
    v *= (1.f / 64.f);
    float rstd = rsqrtf(v + 1e-5f);
    if (live && hlf == 0) {
        float res[8];
#pragma unroll
        for (int k = 0; k < 8; k++)
            res[k] = (o[k] - mu) * rstd * gamma[i * 8 + k] + beta[i * 8 + k];
        float4* op = (float4*)(out + (size_t)node * 64 + i * 8);
        op[0] = make_float4(res[0], res[1], res[2], res[3]);
        op[1] = make_float4(res[4], res[5], res[6], res[7]);
    }
}

extern "C" void kernel_launch(void* const* d_in, const int* in_sizes, int n_in,
                              void* d_out, int out_size, void* d_ws, size_t ws_size,
                              hipStream_t stream) {
    const float* x        = (const float*)d_in[0];
    const int*   ei       = (const int*)  d_in[1];
    const int*   type_ids = (const int*)  d_in[2];
    const float* type_emb = (const float*)d_in[3];
    const float* W1       = (const float*)d_in[4];
    const float* a_src1   = (const float*)d_in[5];
    const float* a_dst1   = (const float*)d_in[6];
    const float* b1       = (const float*)d_in[7];
    const float* W2       = (const float*)d_in[8];
    const float* a_src2   = (const float*)d_in[9];
    const float* a_dst2   = (const float*)d_in[10];
    const float* b2       = (const float*)d_in[11];
    const float* gamma    = (const float*)d_in[12];
    const float* beta     = (const float*)d_in[13];

    int N = in_sizes[0] / 5;
    int E = in_sizes[1] / 2;
    int NBLK = (N + 255) >> 8;

    char* base = (char*)d_ws;
    size_t off = 0;
    auto carve = [&](size_t bytes) { void* p = base + off; off += (bytes + 255) & ~(size_t)255; return p; };
    __half2* h1h = (__half2*)carve((size_t)N * 64 * sizeof(__half));
    _Float16* h2h = (_Float16*)carve((size_t)N * 64 * sizeof(__half));
    char* h3region = (char*)carve((size_t)N * 64 * sizeof(__half));
    _Float16* h3h = (_Float16*)h3region;
    // deg/btot/bbase overlay the h3h region (dead before k_node2m writes h3h)
    int* deg   = (int*)h3region;
    int* btot  = (int*)(h3region + (size_t)N * sizeof(int));
    int* bbase = (int*)(h3region + (size_t)N * sizeof(int) + 4096);
    float* als1  = (float*)carve((size_t)N * 2 * sizeof(float));
    float* ald1  = (float*)carve((size_t)N * 2 * sizeof(float));
    float* als2  = (float*)carve((size_t)N * sizeof(float));
    float* ald2  = (float*)carve((size_t)N * sizeof(float));
    int*   rs    = (int*)carve((size_t)N * sizeof(int));
    int*   cur   = (int*)carve((size_t)N * sizeof(int));
    int*   ssrc  = (int*)carve((size_t)E * sizeof(int) + 256);

    dim3 tb(256);

    k_node1<<<dim3((N + 3) / 4), tb, 0, stream>>>(x, type_ids, type_emb, W1, a_src1, a_dst1,
                                                  h1h, als1, ald1, N);

    hipMemsetAsync(deg, 0, (size_t)N * sizeof(int), stream);
    k_deg<<<dim3(2048), tb, 0, stream>>>(ei, deg, E);
    k_scan1<<<dim3(NBLK), tb, 0, stream>>>(deg, btot, N);
    k_scan2<<<dim3(1), dim3(512), 0, stream>>>(btot, bbase, NBLK);
    k_scan3<<<dim3(NBLK), tb, 0, stream>>>(deg, bbase, rs, cur, N);
    k_scatter<<<dim3(2048), tb, 0, stream>>>(ei, cur, ssrc, E);

    dim3 ng((N + 15) / 16);
    k_gather1<<<ng, tb, 0, stream>>>(rs, cur, ssrc, (const float4*)h1h, als1, ald1, b1,
                                     (float4*)h2h, N);
    k_node2m<<<dim3((N + 63) / 64), tb, 0, stream>>>(h2h, W2, a_src2, a_dst2,
                                                     h3h, als2, ald2, N);
    k_gather2<<<ng, tb, 0, stream>>>(rs, cur, ssrc, (const float4*)h3h, als2, ald2, b2,
                                     gamma, beta, (float*)d_out, N);
}

// Round 5
// 310.535 us; speedup vs baseline: 2.1331x; 2.1331x over previous
//
#include <hip/hip_runtime.h>
#include <hip/hip_fp16.h>

#define NEG_SLOPE 0.2f
#define BKT_SHIFT 8
#define BKT_NODES 256
#define BKT_CAP 10240
#define SRC_SHIFT 18
#define SRC_MASK 0x3FFFF
#define CHUNK 8192
#define NBMAX 512

typedef _Float16 half8 __attribute__((ext_vector_type(8)));
typedef float float4v __attribute__((ext_vector_type(4)));

// ---------------- Kernel: node prep layer 1 ----------------
__global__ void k_node1(const float* __restrict__ x, const int* __restrict__ type_ids,
                        const float* __restrict__ type_emb, const float* __restrict__ W1,
                        const float* __restrict__ a_src1, const float* __restrict__ a_dst1,
                        __half2* __restrict__ h1h, float* __restrict__ als1, float* __restrict__ ald1,
                        int N)
{
    int node = blockIdx.x * 4 + (threadIdx.x >> 6);
    int j = threadIdx.x & 63;
    if (node >= N) return;

    float xin[21];
#pragma unroll
    for (int k = 0; k < 5; k++) xin[k] = x[node * 5 + k];
    int t = type_ids[node];
#pragma unroll
    for (int k = 0; k < 16; k++) xin[5 + k] = type_emb[t * 16 + k];

    float h = 0.f;
#pragma unroll
    for (int k = 0; k < 21; k++) h += xin[k] * W1[k * 64 + j];

    float hn = __shfl_xor(h, 1);
    if ((j & 1) == 0)
        h1h[node * 32 + (j >> 1)] = __floats2half2_rn(h, hn);

    int head = j >> 5, lane = j & 31;
    float ps = h * a_src1[head * 32 + lane];
    float pd = h * a_dst1[head * 32 + lane];
#pragma unroll
    for (int m = 16; m >= 1; m >>= 1) { ps += __shfl_xor(ps, m); pd += __shfl_xor(pd, m); }
    if (lane == 0) { als1[node * 2 + head] = ps; ald1[node * 2 + head] = pd; }
}

// ---------------- CSR build, phase A: 512-thread register-staged bucket append ----------------
__global__ __launch_bounds__(512) void k_bucketA(
        const int* __restrict__ ei, unsigned int* __restrict__ pk,
        int* __restrict__ bcnt, int E, int NBKT)
{
    __shared__ unsigned int stage[CHUNK];
    __shared__ unsigned short stageB[CHUNK];
    __shared__ int cnt[NBMAX];
    __shared__ int excl[NBMAX];
    __shared__ int curp[NBMAX];
    __shared__ int gbase[NBMAX];

    int t = threadIdx.x;
    int e0 = blockIdx.x * CHUNK;
    bool vec4 = ((E & 3) == 0);

    cnt[t] = 0;
    __syncthreads();

    int4 s4[4], d4[4];
    bool val[4];

    if (vec4) {
        // single read: stage 16 edges/thread in registers, count
#pragma unroll
        for (int it = 0; it < 4; it++) {
            int e = e0 + it * 2048 + t * 4;
            val[it] = (e < E);
            if (val[it]) {
                s4[it] = *(const int4*)(ei + e);
                d4[it] = *(const int4*)(ei + (size_t)E + e);
                atomicAdd(&cnt[d4[it].x >> BKT_SHIFT], 1);
                atomicAdd(&cnt[d4[it].y >> BKT_SHIFT], 1);
                atomicAdd(&cnt[d4[it].z >> BKT_SHIFT], 1);
                atomicAdd(&cnt[d4[it].w >> BKT_SHIFT], 1);
            }
        }
    } else {
        for (int i = t; i < CHUNK; i += 512) {
            int e = e0 + i;
            if (e >= E) break;
            atomicAdd(&cnt[ei[E + e] >> BKT_SHIFT], 1);
        }
    }
    __syncthreads();
    int myc = cnt[t];
    __syncthreads();
    // inclusive scan over 512 entries, one per thread
    for (int off = 1; off < NBMAX; off <<= 1) {
        int v = (t >= off) ? cnt[t - off] : 0;
        __syncthreads();
        cnt[t] += v;
        __syncthreads();
    }
    {
        int ex = cnt[t] - myc;
        excl[t] = ex;
        curp[t] = ex;
        if (t < NBKT)
            gbase[t] = (myc > 0) ? atomicAdd(&bcnt[t], myc) : 0;
    }
    __syncthreads();
    // scatter from registers into LDS stage (ordered by bucket)
    if (vec4) {
#pragma unroll
        for (int it = 0; it < 4; it++) {
            if (!val[it]) continue;
            int ss[4] = {s4[it].x, s4[it].y, s4[it].z, s4[it].w};
            int dd[4] = {d4[it].x, d4[it].y, d4[it].z, d4[it].w};
#pragma unroll
            for (int k = 0; k < 4; k++) {
                int b = dd[k] >> BKT_SHIFT;
                int p = atomicAdd(&curp[b], 1);
                stage[p] = (unsigned)ss[k] | ((unsigned)(dd[k] & (BKT_NODES - 1)) << SRC_SHIFT);
                stageB[p] = (unsigned short)b;
            }
        }
    } else {
        for (int i = t; i < CHUNK; i += 512) {
            int e = e0 + i;
            if (e >= E) break;
            int s = ei[e], d = ei[E + e];
            int b = d >> BKT_SHIFT;
            int p = atomicAdd(&curp[b], 1);
            stage[p] = (unsigned)s | ((unsigned)(d & (BKT_NODES - 1)) << SRC_SHIFT);
            stageB[p] = (unsigned short)b;
        }
    }
    __syncthreads();
    int total = E - e0; if (total > CHUNK) total = CHUNK;
    for (int i = t; i < total; i += 512) {
        int b = stageB[i];
        int idx = gbase[b] + (i - excl[b]);
        if (idx < BKT_CAP) pk[(size_t)b * BKT_CAP + idx] = stage[i];
    }
}

// ---------------- CSR build, phase B: 512-thread per-bucket counting sort ----------------
__global__ __launch_bounds__(512) void k_build(
        const unsigned int* __restrict__ pk, const int* __restrict__ bcnt,
        int* __restrict__ rs, int* __restrict__ cur,
        int* __restrict__ ssrc, int N)
{
    __shared__ unsigned int vals[BKT_CAP];
    __shared__ int cnt[BKT_NODES];
    __shared__ int cursor[BKT_NODES];
    __shared__ int orig[BKT_NODES];
    __shared__ int red[512];
    int b = blockIdx.x;
    int t = threadIdx.x;
    int nb = min(bcnt[b], BKT_CAP);

    int part = 0;
    for (int i = t; i < b; i += 512) part += min(bcnt[i], BKT_CAP);
    red[t] = part;
    if (t < BKT_NODES) cnt[t] = 0;
    __syncthreads();
    for (int off = 256; off; off >>= 1) {
        if (t < off) red[t] += red[t + off];
        __syncthreads();
    }
    int bs = red[0];

    const unsigned int* mypk = pk + (size_t)b * BKT_CAP;
    int nb4 = nb & ~3;
    for (int e = t * 4; e < nb4; e += 2048) {
        uint4 v = *(const uint4*)(mypk + e);
        *(uint4*)(vals + e) = v;
        atomicAdd(&cnt[v.x >> SRC_SHIFT], 1);
        atomicAdd(&cnt[v.y >> SRC_SHIFT], 1);
        atomicAdd(&cnt[v.z >> SRC_SHIFT], 1);
        atomicAdd(&cnt[v.w >> SRC_SHIFT], 1);
    }
    for (int e = nb4 + t; e < nb; e += 512) {
        unsigned int v = mypk[e];
        vals[e] = v;
        atomicAdd(&cnt[v >> SRC_SHIFT], 1);
    }
    __syncthreads();
    if (t < BKT_NODES) orig[t] = cnt[t];
    __syncthreads();
    // inclusive scan over 256 node counters (first 256 threads active)
    for (int off = 1; off < BKT_NODES; off <<= 1) {
        int v = (t < BKT_NODES && t >= off) ? cnt[t - off] : 0;
        __syncthreads();
        if (t < BKT_NODES) cnt[t] += v;
        __syncthreads();
    }
    if (t < BKT_NODES) {
        int c = orig[t];
        int ex = cnt[t] - c;
        cursor[t] = ex;
        int node = (b << BKT_SHIFT) + t;
        if (node < N) { rs[node] = bs + ex; cur[node] = bs + ex + c; }
    }
    __syncthreads();
    for (int e = t; e < nb; e += 512) {
        unsigned int w = vals[e];
        int p = atomicAdd(&cursor[w >> SRC_SHIFT], 1);
        ssrc[bs + p] = (int)(w & SRC_MASK);
    }
}

// ---------------- Gather layer 1: 16 lanes/node (2x8 halves), 4 nodes/wave, fp32 acc ----------------
__global__ void k_gather1(const int* __restrict__ rs, const int* __restrict__ cur,
                          const int* __restrict__ ssrc, const float4* __restrict__ h4,
                          const float* __restrict__ als1, const float* __restrict__ ald1,
                          const float* __restrict__ b1, float4* __restrict__ h2h4, int N)
{
    int t = threadIdx.x;
    int l = t & 63;
    int q = l & 15;          // lane within node group
    int i = q & 7;           // channel octet owner (channels 8i..8i+7)
    int hlf = q >> 3;        // slot-half
    int grpbase = l & 48;
    int head = i >> 2;

    int node = blockIdx.x * 16 + (t >> 4);
    bool live = node < N;
    int node_c = live ? node : (N - 1);

    int beg = rs[node_c];
    int cnt = live ? (cur[node_c] - beg) : 0;

    float ad0 = ald1[node_c * 2 + 0];
    float ad1 = ald1[node_c * 2 + 1];
    float ad = head ? ad1 : ad0;

    // wave-wide max degree (cnt uniform within each 16-lane group)
    int mc = cnt;
    mc = max(mc, __shfl_xor(mc, 16));
    mc = max(mc, __shfl_xor(mc, 32));

    float acc[8];
#pragma unroll
    for (int k = 0; k < 8; k++) acc[k] = 0.f;
    float wsum = 0.f;

    for (int b = 0; b < mc; b += 16) {
        // phase 1: lane q owns slot b+q of its group's list
        int slot = b + q;
        bool valid = slot < cnt;
        int idx = valid ? (beg + slot) : 0;
        int s = ssrc[idx];
        if (!valid) s = node_c;
        float2 al = *(const float2*)(als1 + (size_t)s * 2);
        float lg0 = al.x + ad0; lg0 = (lg0 >= 0.f) ? lg0 : NEG_SLOPE * lg0;
        float lg1 = al.y + ad1; lg1 = (lg1 >= 0.f) ? lg1 : NEG_SLOPE * lg1;
        float w0 = valid ? __expf(lg0) : 0.f;
        float w1 = valid ? __expf(lg1) : 0.f;
        __half2 wp = __floats2half2_rn(w0, w1);
        unsigned wpi = *(unsigned*)&wp;

        // phase 2: 8 rounds; each half processes its 8 slots (2 edges/node/round)
#pragma unroll
        for (int r = 0; r < 8; r++) {
            int srcl = grpbase + hlf * 8 + r;
            int sr = __shfl(s, srcl);
            unsigned wri = __shfl(wpi, srcl);
            __half2 wh = *(__half2*)&wri;
            float w = head ? __high2float(wh) : __low2float(wh);
            float4 rv = h4[(size_t)sr * 8 + i];
            const __half* hp = (const __half*)&rv;
#pragma unroll
            for (int k = 0; k < 8; k++)
                acc[k] = fmaf(w, __half2float(hp[k]), acc[k]);
            wsum += w;
        }
    }

    // merge the two halves
#pragma unroll
    for (int k = 0; k < 8; k++) acc[k] += __shfl_xor(acc[k], 8);
    wsum += __shfl_xor(wsum, 8);

    // self loop
    {
        float lg = als1[node_c * 2 + head] + ad;
        lg = (lg >= 0.f) ? lg : NEG_SLOPE * lg;
        float w = __expf(lg);
        float4 rv = h4[(size_t)node_c * 8 + i];
        const __half* hp = (const __half*)&rv;
#pragma unroll
        for (int k = 0; k < 8; k++)
            acc[k] = fmaf(w, __half2float(hp[k]), acc[k]);
        wsum += w;
    }

    float inv = 1.f / (wsum + 1e-16f);
    if (live && hlf == 0) {
        union { float4 f4; __half2 h2[4]; } u;
#pragma unroll
        for (int c = 0; c < 4; c++) {
            float v0 = fmaxf(acc[2*c]   * inv + b1[i * 8 + 2*c],     0.f);
            float v1 = fmaxf(acc[2*c+1] * inv + b1[i * 8 + 2*c + 1], 0.f);
            u.h2[c] = __floats2half2_rn(v0, v1);
        }
        h2h4[(size_t)node * 8 + i] = u.f4;
    }
}

// ---------------- MFMA projection: h3 = h2 @ W2 (fp16 in, fp32 acc) + logits ----------------
__global__ __launch_bounds__(256) void k_node2m(
        const _Float16* __restrict__ h2h, const float* __restrict__ W2,
        const float* __restrict__ a_src2, const float* __restrict__ a_dst2,
        _Float16* __restrict__ h3h, float* __restrict__ als2, float* __restrict__ ald2, int N)
{
    __shared__ _Float16 w2t[64][72];
    __shared__ float h3t[4][16][65];
    int t = threadIdx.x;
    for (int e = t; e < 4096; e += 256) {
        int k = e >> 6, n = e & 63;
        w2t[n][k] = (_Float16)W2[e];
    }
    __syncthreads();

    int w = t >> 6, l = t & 63;
    int l15 = l & 15, quad = l >> 4;
    int nodebase = blockIdx.x * 64 + w * 16;

    int arow = nodebase + l15;
    if (arow >= N) arow = N - 1;
    const half8* ap = (const half8*)(h2h + (size_t)arow * 64 + quad * 8);
    half8 a0 = ap[0];
    half8 a1 = ap[4];
    float4v accs[4];
#pragma unroll
    for (int nt = 0; nt < 4; nt++) {
        half8 b0 = *(const half8*)(&w2t[nt * 16 + l15][quad * 8]);
        half8 b1 = *(const half8*)(&w2t[nt * 16 + l15][32 + quad * 8]);
        float4v c = {0.f, 0.f, 0.f, 0.f};
        c = __builtin_amdgcn_mfma_f32_16x16x32_f16(a0, b0, c, 0, 0, 0);
        c = __builtin_amdgcn_mfma_f32_16x16x32_f16(a1, b1, c, 0, 0, 0);
        accs[nt] = c;
    }
#pragma unroll
    for (int nt = 0; nt < 4; nt++)
#pragma unroll
        for (int r = 0; r < 4; r++)
            h3t[w][quad * 4 + r][nt * 16 + l15] = accs[nt][r];
    __syncthreads();

    int m = l >> 2, part = l & 3;
    int g = blockIdx.x * 64 + w * 16 + m;
    float ps = 0.f, pd = 0.f;
    union { float4 f4[2]; _Float16 h[16]; } u;
#pragma unroll
    for (int c = 0; c < 16; c++) {
        float v = h3t[w][m][part * 16 + c];
        ps += v * a_src2[part * 16 + c];
        pd += v * a_dst2[part * 16 + c];
        u.h[c] = (_Float16)v;
    }
    if (g < N) {
        float4* dst = (float4*)(h3h + (size_t)g * 64) + part * 2;
        dst[0] = u.f4[0];
        dst[1] = u.f4[1];
    }
    ps += __shfl_xor(ps, 1); ps += __shfl_xor(ps, 2);
    pd += __shfl_xor(pd, 1); pd += __shfl_xor(pd, 2);
    if (part == 0 && g < N) { als2[g] = ps; ald2[g] = pd; }
}

// ---------------- Gather layer 2: 16 lanes/node, 4 nodes/wave + LayerNorm ----------------
__global__ void k_gather2(const int* __restrict__ rs, const int* __restrict__ cur,
                          const int* __restrict__ ssrc, const float4* __restrict__ h4,
                          const float* __restrict__ als2, const float* __restrict__ ald2,
                          const float* __restrict__ b2, const float* __restrict__ gamma,
                          const float* __restrict__ beta, float* __restrict__ out, int N)
{
    int t = threadIdx.x;
    int l = t & 63;
    int q = l & 15;
    int i = q & 7;
    int hlf = q >> 3;
    int grpbase = l & 48;

    int node = blockIdx.x * 16 + (t >> 4);
    bool live = node < N;
    int node_c = live ? node : (N - 1);

    int beg = rs[node_c];
    int cnt = live ? (cur[node_c] - beg) : 0;
    float ad = ald2[node_c];

    int mc = cnt;
    mc = max(mc, __shfl_xor(mc, 16));
    mc = max(mc, __shfl_xor(mc, 32));

    float acc[8];
#pragma unroll
    for (int k = 0; k < 8; k++) acc[k] = 0.f;
    float wsum = 0.f;

    for (int b = 0; b < mc; b += 16) {
        int slot = b + q;
        bool valid = slot < cnt;
        int idx = valid ? (beg + slot) : 0;
        int s = ssrc[idx];
        if (!valid) s = node_c;
        float lg = als2[s] + ad;
        lg = (lg >= 0.f) ? lg : NEG_SLOPE * lg;
        float w = valid ? __expf(lg) : 0.f;

#pragma unroll
        for (int r = 0; r < 8; r++) {
            int srcl = grpbase + hlf * 8 + r;
            int sr = __shfl(s, srcl);
            float wr = __shfl(w, srcl);
            float4 rv = h4[(size_t)sr * 8 + i];
            const __half* hp = (const __half*)&rv;
#pragma unroll
            for (int k = 0; k < 8; k++)
                acc[k] = fmaf(wr, __half2float(hp[k]), acc[k]);
            wsum += wr;
        }
    }

    // merge halves
#pragma unroll
    for (int k = 0; k < 8; k++) acc[k] += __shfl_xor(acc[k], 8);
    wsum += __shfl_xor(wsum, 8);

    // self loop
    {
        float lg = als2[node_c] + ad;
        lg = (lg >= 0.f) ? lg : NEG_SLOPE * lg;
        float w = __expf(lg);
        float4 rv = h4[(size_t)node_c * 8 + i];
        const __half* hp = (const __half*)&rv;
#pragma unroll
        for (int k = 0; k < 8; k++)
            acc[k] = fmaf(w, __half2float(hp[k]), acc[k]);
        wsum += w;
    }

    float inv = 1.f / (wsum + 1e-16f);
    float o[8];
    float s = 0.f;
#pragma unroll
    for (int k = 0; k < 8; k++) { o[k] = acc[k] * inv + b2[i * 8 + k]; s += o[k]; }
    s += __shfl_xor(s, 1); s += __shfl_xor(s, 2); s += __shfl_xor(s, 4);
    float mu = s * (1.f / 64.f);
    float v = 0.f;
#pragma unroll
    for (int k = 0; k < 8; k++) { float d = o[k] - mu; v += d * d; }
    v += __shfl_xor(v, 1); v += __shfl_xor(v, 2); v += __shfl_xor(v, 4);
    v *= (1.f / 64.f);
    float rstd = rsqrtf(v + 1e-5f);
    if (live && hlf == 0) {
        float res[8];
#pragma unroll
        for (int k = 0; k < 8; k++)
            res[k] = (o[k] - mu) * rstd * gamma[i * 8 + k] + beta[i * 8 + k];
        float4* op = (float4*)(out + (size_t)node * 64 + i * 8);
        op[0] = make_float4(res[0], res[1], res[2], res[3]);
        op[1] = make_float4(res[4], res[5], res[6], res[7]);
    }
}

extern "C" void kernel_launch(void* const* d_in, const int* in_sizes, int n_in,
                              void* d_out, int out_size, void* d_ws, size_t ws_size,
                              hipStream_t stream) {
    const float* x        = (const float*)d_in[0];
    const int*   ei       = (const int*)  d_in[1];
    const int*   type_ids = (const int*)  d_in[2];
    const float* type_emb = (const float*)d_in[3];
    const float* W1       = (const float*)d_in[4];
    const float* a_src1   = (const float*)d_in[5];
    const float* a_dst1   = (const float*)d_in[6];
    const float* b1       = (const float*)d_in[7];
    const float* W2       = (const float*)d_in[8];
    const float* a_src2   = (const float*)d_in[9];
    const float* a_dst2   = (const float*)d_in[10];
    const float* b2       = (const float*)d_in[11];
    const float* gamma    = (const float*)d_in[12];
    const float* beta     = (const float*)d_in[13];

    int N = in_sizes[0] / 5;
    int E = in_sizes[1] / 2;
    int NBKT = (N + BKT_NODES - 1) >> BKT_SHIFT;

    // Workspace: pk (16 MB, dead after k_build) overlaid on h2h/h3h (25.6 MB).
    char* base = (char*)d_ws;
    size_t off = 0;
    auto carve = [&](size_t bytes) { void* p = base + off; off += (bytes + 255) & ~(size_t)255; return p; };
    __half2* h1h = (__half2*)carve((size_t)N * 64 * sizeof(__half));
    size_t pk_bytes = (size_t)NBKT * BKT_CAP * sizeof(unsigned int);
    size_t h23_bytes = 2 * (size_t)N * 64 * sizeof(__half);
    char* uni = (char*)carve(pk_bytes > h23_bytes ? pk_bytes : h23_bytes);
    _Float16* h2h = (_Float16*)uni;
    _Float16* h3h = (_Float16*)(uni + (size_t)N * 64 * sizeof(__half));
    unsigned int* pk = (unsigned int*)uni;
    float* als1  = (float*)carve((size_t)N * 2 * sizeof(float));
    float* ald1  = (float*)carve((size_t)N * 2 * sizeof(float));
    float* als2  = (float*)carve((size_t)N * sizeof(float));
    float* ald2  = (float*)carve((size_t)N * sizeof(float));
    int*   rs    = (int*)carve((size_t)N * sizeof(int));
    int*   cur   = (int*)carve((size_t)N * sizeof(int));
    int*   bcnt  = (int*)carve(1024 * sizeof(int));
    int*   ssrc  = (int*)carve((size_t)E * sizeof(int) + 256);

    dim3 tb(256);
    dim3 tb512(512);

    k_node1<<<dim3((N + 3) / 4), tb, 0, stream>>>(x, type_ids, type_emb, W1, a_src1, a_dst1,
                                                  h1h, als1, ald1, N);

    hipMemsetAsync(bcnt, 0, NBKT * sizeof(int), stream);
    k_bucketA<<<dim3((E + CHUNK - 1) / CHUNK), tb512, 0, stream>>>(ei, pk, bcnt, E, NBKT);
    k_build<<<dim3(NBKT), tb512, 0, stream>>>(pk, bcnt, rs, cur, ssrc, N);

    dim3 ng((N + 15) / 16);
    k_gather1<<<ng, tb, 0, stream>>>(rs, cur, ssrc, (const float4*)h1h, als1, ald1, b1,
                                     (float4*)h2h, N);
    k_node2m<<<dim3((N + 63) / 64), tb, 0, stream>>>(h2h, W2, a_src2, a_dst2,
                                                     h3h, als2, ald2, N);
    k_gather2<<<ng, tb, 0, stream>>>(rs, cur, ssrc, (const float4*)h3h, als2, ald2, b2,
                                     gamma, beta, (float*)d_out, N);
}

// Round 6
// 308.881 us; speedup vs baseline: 2.1445x; 1.0054x over previous
//
#include <hip/hip_runtime.h>
#include <hip/hip_fp16.h>

#define NEG_SLOPE 0.2f
#define BKT_SHIFT 8
#define BKT_NODES 256
#define BKT_CAP 10240
#define SRC_SHIFT 18
#define SRC_MASK 0x3FFFF
#define CHUNK 8192
#define NBMAX 512

typedef _Float16 half8 __attribute__((ext_vector_type(8)));
typedef float float4v __attribute__((ext_vector_type(4)));

__device__ __forceinline__ int wave_iscan(int v, int lane) {
#pragma unroll
    for (int off = 1; off < 64; off <<= 1) {
        int u = __shfl_up(v, off);
        if (lane >= off) v += u;
    }
    return v;
}

// ---------------- Kernel: node prep layer 1 ----------------
__global__ void k_node1(const float* __restrict__ x, const int* __restrict__ type_ids,
                        const float* __restrict__ type_emb, const float* __restrict__ W1,
                        const float* __restrict__ a_src1, const float* __restrict__ a_dst1,
                        __half2* __restrict__ h1h, float* __restrict__ als1, float* __restrict__ ald1,
                        int N)
{
    int node = blockIdx.x * 4 + (threadIdx.x >> 6);
    int j = threadIdx.x & 63;
    if (node >= N) return;

    float xin[21];
#pragma unroll
    for (int k = 0; k < 5; k++) xin[k] = x[node * 5 + k];
    int t = type_ids[node];
#pragma unroll
    for (int k = 0; k < 16; k++) xin[5 + k] = type_emb[t * 16 + k];

    float h = 0.f;
#pragma unroll
    for (int k = 0; k < 21; k++) h += xin[k] * W1[k * 64 + j];

    float hn = __shfl_xor(h, 1);
    if ((j & 1) == 0)
        h1h[node * 32 + (j >> 1)] = __floats2half2_rn(h, hn);

    int head = j >> 5, lane = j & 31;
    float ps = h * a_src1[head * 32 + lane];
    float pd = h * a_dst1[head * 32 + lane];
#pragma unroll
    for (int m = 16; m >= 1; m >>= 1) { ps += __shfl_xor(ps, m); pd += __shfl_xor(pd, m); }
    if (lane == 0) { als1[node * 2 + head] = ps; ald1[node * 2 + head] = pd; }
}

// ---------------- CSR build, phase A: 512-thread register-staged bucket append ----------------
__global__ __launch_bounds__(512) void k_bucketA(
        const int* __restrict__ ei, unsigned int* __restrict__ pk,
        int* __restrict__ bcnt, int E, int NBKT)
{
    __shared__ unsigned int stage[CHUNK];
    __shared__ unsigned short stageB[CHUNK];
    __shared__ int cnt[NBMAX];
    __shared__ int excl[NBMAX];
    __shared__ int curp[NBMAX];
    __shared__ int gbase[NBMAX];
    __shared__ int wpart[8];

    int t = threadIdx.x;
    int lane = t & 63, wv = t >> 6;
    int e0 = blockIdx.x * CHUNK;
    bool vec4 = ((E & 3) == 0);

    cnt[t] = 0;
    __syncthreads();

    int4 s4[4], d4[4];
    bool val[4];

    if (vec4) {
        // single read: stage 16 edges/thread in registers, count
#pragma unroll
        for (int it = 0; it < 4; it++) {
            int e = e0 + it * 2048 + t * 4;
            val[it] = (e < E);
            if (val[it]) {
                s4[it] = *(const int4*)(ei + e);
                d4[it] = *(const int4*)(ei + (size_t)E + e);
                atomicAdd(&cnt[d4[it].x >> BKT_SHIFT], 1);
                atomicAdd(&cnt[d4[it].y >> BKT_SHIFT], 1);
                atomicAdd(&cnt[d4[it].z >> BKT_SHIFT], 1);
                atomicAdd(&cnt[d4[it].w >> BKT_SHIFT], 1);
            }
        }
    } else {
        for (int i = t; i < CHUNK; i += 512) {
            int e = e0 + i;
            if (e >= E) break;
            atomicAdd(&cnt[ei[E + e] >> BKT_SHIFT], 1);
        }
    }
    __syncthreads();
    int myc = cnt[t];
    // shfl-based inclusive scan over 512 entries (8 waves + fixup)
    int incl = wave_iscan(myc, lane);
    if (lane == 63) wpart[wv] = incl;
    __syncthreads();
#pragma unroll
    for (int k = 0; k < 8; k++)
        if (k < wv) incl += wpart[k];
    {
        int ex = incl - myc;
        excl[t] = ex;
        curp[t] = ex;
        if (t < NBKT)
            gbase[t] = (myc > 0) ? atomicAdd(&bcnt[t], myc) : 0;
    }
    __syncthreads();
    // scatter from registers into LDS stage (ordered by bucket)
    if (vec4) {
#pragma unroll
        for (int it = 0; it < 4; it++) {
            if (!val[it]) continue;
            int ss[4] = {s4[it].x, s4[it].y, s4[it].z, s4[it].w};
            int dd[4] = {d4[it].x, d4[it].y, d4[it].z, d4[it].w};
#pragma unroll
            for (int k = 0; k < 4; k++) {
                int b = dd[k] >> BKT_SHIFT;
                int p = atomicAdd(&curp[b], 1);
                stage[p] = (unsigned)ss[k] | ((unsigned)(dd[k] & (BKT_NODES - 1)) << SRC_SHIFT);
                stageB[p] = (unsigned short)b;
            }
        }
    } else {
        for (int i = t; i < CHUNK; i += 512) {
            int e = e0 + i;
            if (e >= E) break;
            int s = ei[e], d = ei[E + e];
            int b = d >> BKT_SHIFT;
            int p = atomicAdd(&curp[b], 1);
            stage[p] = (unsigned)s | ((unsigned)(d & (BKT_NODES - 1)) << SRC_SHIFT);
            stageB[p] = (unsigned short)b;
        }
    }
    __syncthreads();
    int total = E - e0; if (total > CHUNK) total = CHUNK;
    for (int i = t; i < total; i += 512) {
        int b = stageB[i];
        int idx = gbase[b] + (i - excl[b]);
        if (idx < BKT_CAP) pk[(size_t)b * BKT_CAP + idx] = stage[i];
    }
}

// ---------------- bucket-base exclusive scan (one small block) ----------------
__global__ __launch_bounds__(512) void k_scanb(
        const int* __restrict__ bcnt, int* __restrict__ bbase, int NBKT)
{
    __shared__ int wpart[8];
    int t = threadIdx.x;
    int lane = t & 63, wv = t >> 6;
    int v = (t < NBKT) ? min(bcnt[t], BKT_CAP) : 0;
    int incl = wave_iscan(v, lane);
    if (lane == 63) wpart[wv] = incl;
    __syncthreads();
#pragma unroll
    for (int k = 0; k < 8; k++)
        if (k < wv) incl += wpart[k];
    if (t < NBKT) bbase[t] = incl - v;
}

// ---------------- CSR build, phase B: streaming per-bucket counting sort ----------------
__global__ __launch_bounds__(512) void k_build(
        const unsigned int* __restrict__ pk, const int* __restrict__ bcnt,
        const int* __restrict__ bbase,
        int* __restrict__ rs, int* __restrict__ cur,
        int* __restrict__ ssrc, int N)
{
    __shared__ int cnt[BKT_NODES];
    __shared__ int cursor[BKT_NODES];
    __shared__ int wpart[4];
    int b = blockIdx.x;
    int t = threadIdx.x;
    int lane = t & 63, wv = t >> 6;
    int nb = min(bcnt[b], BKT_CAP);
    int bs = bbase[b];

    if (t < BKT_NODES) cnt[t] = 0;
    __syncthreads();

    const unsigned int* mypk = pk + (size_t)b * BKT_CAP;
    int nb4 = nb & ~3;
    for (int e = t * 4; e < nb4; e += 2048) {
        uint4 v = *(const uint4*)(mypk + e);
        atomicAdd(&cnt[v.x >> SRC_SHIFT], 1);
        atomicAdd(&cnt[v.y >> SRC_SHIFT], 1);
        atomicAdd(&cnt[v.z >> SRC_SHIFT], 1);
        atomicAdd(&cnt[v.w >> SRC_SHIFT], 1);
    }
    for (int e = nb4 + t; e < nb; e += 512) {
        atomicAdd(&cnt[mypk[e] >> SRC_SHIFT], 1);
    }
    __syncthreads();
    // shfl scan over 256 counters (first 4 waves)
    if (t < BKT_NODES) {
        int myc = cnt[t];
        int incl = wave_iscan(myc, lane);
        if (lane == 63) wpart[wv] = incl;
        __syncthreads();
#pragma unroll
        for (int k = 0; k < 4; k++)
            if (k < wv) incl += wpart[k];
        int ex = incl - myc;
        cursor[t] = ex;
        int node = (b << BKT_SHIFT) + t;
        if (node < N) { rs[node] = bs + ex; cur[node] = bs + ex + myc; }
    } else {
        __syncthreads();
    }
    __syncthreads();
    // scatter: stream pk again (L2-hot) and place via LDS cursors
    for (int e = t; e < nb; e += 512) {
        unsigned int w = mypk[e];
        int p = atomicAdd(&cursor[w >> SRC_SHIFT], 1);
        ssrc[bs + p] = (int)(w & SRC_MASK);
    }
}

// ---------------- Gather layer 1: 16 lanes/node (2x8 halves), 4 nodes/wave, fp32 acc ----------------
__global__ void k_gather1(const int* __restrict__ rs, const int* __restrict__ cur,
                          const int* __restrict__ ssrc, const float4* __restrict__ h4,
                          const float* __restrict__ als1, const float* __restrict__ ald1,
                          const float* __restrict__ b1, float4* __restrict__ h2h4, int N)
{
    int t = threadIdx.x;
    int l = t & 63;
    int q = l & 15;          // lane within node group
    int i = q & 7;           // channel octet owner (channels 8i..8i+7)
    int hlf = q >> 3;        // slot-half
    int grpbase = l & 48;
    int head = i >> 2;

    int node = blockIdx.x * 16 + (t >> 4);
    bool live = node < N;
    int node_c = live ? node : (N - 1);

    int beg = rs[node_c];
    int cnt = live ? (cur[node_c] - beg) : 0;

    float ad0 = ald1[node_c * 2 + 0];
    float ad1 = ald1[node_c * 2 + 1];
    float ad = head ? ad1 : ad0;

    // wave-wide max degree (cnt uniform within each 16-lane group)
    int mc = cnt;
    mc = max(mc, __shfl_xor(mc, 16));
    mc = max(mc, __shfl_xor(mc, 32));

    float acc[8];
#pragma unroll
    for (int k = 0; k < 8; k++) acc[k] = 0.f;
    float wsum = 0.f;

    for (int b = 0; b < mc; b += 16) {
        // phase 1: lane q owns slot b+q of its group's list
        int slot = b + q;
        bool valid = slot < cnt;
        int idx = valid ? (beg + slot) : 0;
        int s = ssrc[idx];
        if (!valid) s = node_c;
        float2 al = *(const float2*)(als1 + (size_t)s * 2);
        float lg0 = al.x + ad0; lg0 = (lg0 >= 0.f) ? lg0 : NEG_SLOPE * lg0;
        float lg1 = al.y + ad1; lg1 = (lg1 >= 0.f) ? lg1 : NEG_SLOPE * lg1;
        float w0 = valid ? __expf(lg0) : 0.f;
        float w1 = valid ? __expf(lg1) : 0.f;
        __half2 wp = __floats2half2_rn(w0, w1);
        unsigned wpi = *(unsigned*)&wp;

        // phase 2: 8 rounds; each half processes its 8 slots (2 edges/node/round)
#pragma unroll
        for (int r = 0; r < 8; r++) {
            int srcl = grpbase + hlf * 8 + r;
            int sr = __shfl(s, srcl);
            unsigned wri = __shfl(wpi, srcl);
            __half2 wh = *(__half2*)&wri;
            float w = head ? __high2float(wh) : __low2float(wh);
            float4 rv = h4[(size_t)sr * 8 + i];
            const __half* hp = (const __half*)&rv;
#pragma unroll
            for (int k = 0; k < 8; k++)
                acc[k] = fmaf(w, __half2float(hp[k]), acc[k]);
            wsum += w;
        }
    }

    // merge the two halves
#pragma unroll
    for (int k = 0; k < 8; k++) acc[k] += __shfl_xor(acc[k], 8);
    wsum += __shfl_xor(wsum, 8);

    // self loop
    {
        float lg = als1[node_c * 2 + head] + ad;
        lg = (lg >= 0.f) ? lg : NEG_SLOPE * lg;
        float w = __expf(lg);
        float4 rv = h4[(size_t)node_c * 8 + i];
        const __half* hp = (const __half*)&rv;
#pragma unroll
        for (int k = 0; k < 8; k++)
            acc[k] = fmaf(w, __half2float(hp[k]), acc[k]);
        wsum += w;
    }

    float inv = 1.f / (wsum + 1e-16f);
    if (live && hlf == 0) {
        union { float4 f4; __half2 h2[4]; } u;
#pragma unroll
        for (int c = 0; c < 4; c++) {
            float v0 = fmaxf(acc[2*c]   * inv + b1[i * 8 + 2*c],     0.f);
            float v1 = fmaxf(acc[2*c+1] * inv + b1[i * 8 + 2*c + 1], 0.f);
            u.h2[c] = __floats2half2_rn(v0, v1);
        }
        h2h4[(size_t)node * 8 + i] = u.f4;
    }
}

// ---------------- MFMA projection: h3 = h2 @ W2 (fp16 in, fp32 acc) + logits ----------------
__global__ __launch_bounds__(256) void k_node2m(
        const _Float16* __restrict__ h2h, const float* __restrict__ W2,
        const float* __restrict__ a_src2, const float* __restrict__ a_dst2,
        _Float16* __restrict__ h3h, float* __restrict__ als2, float* __restrict__ ald2, int N)
{
    __shared__ _Float16 w2t[64][72];
    __shared__ float h3t[4][16][65];
    int t = threadIdx.x;
    for (int e = t; e < 4096; e += 256) {
        int k = e >> 6, n = e & 63;
        w2t[n][k] = (_Float16)W2[e];
    }
    __syncthreads();

    int w = t >> 6, l = t & 63;
    int l15 = l & 15, quad = l >> 4;
    int nodebase = blockIdx.x * 64 + w * 16;

    int arow = nodebase + l15;
    if (arow >= N) arow = N - 1;
    const half8* ap = (const half8*)(h2h + (size_t)arow * 64 + quad * 8);
    half8 a0 = ap[0];
    half8 a1 = ap[4];
    float4v accs[4];
#pragma unroll
    for (int nt = 0; nt < 4; nt++) {
        half8 b0 = *(const half8*)(&w2t[nt * 16 + l15][quad * 8]);
        half8 b1 = *(const half8*)(&w2t[nt * 16 + l15][32 + quad * 8]);
        float4v c = {0.f, 0.f, 0.f, 0.f};
        c = __builtin_amdgcn_mfma_f32_16x16x32_f16(a0, b0, c, 0, 0, 0);
        c = __builtin_amdgcn_mfma_f32_16x16x32_f16(a1, b1, c, 0, 0, 0);
        accs[nt] = c;
    }
#pragma unroll
    for (int nt = 0; nt < 4; nt++)
#pragma unroll
        for (int r = 0; r < 4; r++)
            h3t[w][quad * 4 + r][nt * 16 + l15] = accs[nt][r];
    __syncthreads();

    int m = l >> 2, part = l & 3;
    int g = blockIdx.x * 64 + w * 16 + m;
    float ps = 0.f, pd = 0.f;
    union { float4 f4[2]; _Float16 h[16]; } u;
#pragma unroll
    for (int c = 0; c < 16; c++) {
        float v = h3t[w][m][part * 16 + c];
        ps += v * a_src2[part * 16 + c];
        pd += v * a_dst2[part * 16 + c];
        u.h[c] = (_Float16)v;
    }
    if (g < N) {
        float4* dst = (float4*)(h3h + (size_t)g * 64) + part * 2;
        dst[0] = u.f4[0];
        dst[1] = u.f4[1];
    }
    ps += __shfl_xor(ps, 1); ps += __shfl_xor(ps, 2);
    pd += __shfl_xor(pd, 1); pd += __shfl_xor(pd, 2);
    if (part == 0 && g < N) { als2[g] = ps; ald2[g] = pd; }
}

// ---------------- Gather layer 2: 16 lanes/node, 4 nodes/wave + LayerNorm ----------------
__global__ void k_gather2(const int* __restrict__ rs, const int* __restrict__ cur,
                          const int* __restrict__ ssrc, const float4* __restrict__ h4,
                          const float* __restrict__ als2, const float* __restrict__ ald2,
                          const float* __restrict__ b2, const float* __restrict__ gamma,
                          const float* __restrict__ beta, float* __restrict__ out, int N)
{
    int t = threadIdx.x;
    int l = t & 63;
    int q = l & 15;
    int i = q & 7;
    int hlf = q >> 3;
    int grpbase = l & 48;

    int node = blockIdx.x * 16 + (t >> 4);
    bool live = node < N;
    int node_c = live ? node : (N - 1);

    int beg = rs[node_c];
    int cnt = live ? (cur[node_c] - beg) : 0;
    float ad = ald2[node_c];

    int mc = cnt;
    mc = max(mc, __shfl_xor(mc, 16));
    mc = max(mc, __shfl_xor(mc, 32));

    float acc[8];
#pragma unroll
    for (int k = 0; k < 8; k++) acc[k] = 0.f;
    float wsum = 0.f;

    for (int b = 0; b < mc; b += 16) {
        int slot = b + q;
        bool valid = slot < cnt;
        int idx = valid ? (beg + slot) : 0;
        int s = ssrc[idx];
        if (!valid) s = node_c;
        float lg = als2[s] + ad;
        lg = (lg >= 0.f) ? lg : NEG_SLOPE * lg;
        float w = valid ? __expf(lg) : 0.f;

#pragma unroll
        for (int r = 0; r < 8; r++) {
            int srcl = grpbase + hlf * 8 + r;
            int sr = __shfl(s, srcl);
            float wr = __shfl(w, srcl);
            float4 rv = h4[(size_t)sr * 8 + i];
            const __half* hp = (const __half*)&rv;
#pragma unroll
            for (int k = 0; k < 8; k++)
                acc[k] = fmaf(wr, __half2float(hp[k]), acc[k]);
            wsum += wr;
        }
    }

    // merge halves
#pragma unroll
    for (int k = 0; k < 8; k++) acc[k] += __shfl_xor(acc[k], 8);
    wsum += __shfl_xor(wsum, 8);

    // self loop
    {
        float lg = als2[node_c] + ad;
        lg = (lg >= 0.f) ? lg : NEG_SLOPE * lg;
        float w = __expf(lg);
        float4 rv = h4[(size_t)node_c * 8 + i];
        const __half* hp = (const __half*)&rv;
#pragma unroll
        for (int k = 0; k < 8; k++)
            acc[k] = fmaf(w, __half2float(hp[k]), acc[k]);
        wsum += w;
    }

    float inv = 1.f / (wsum + 1e-16f);
    float o[8];
    float s = 0.f;
#pragma unroll
    for (int k = 0; k < 8; k++) { o[k] = acc[k] * inv + b2[i * 8 + k]; s += o[k]; }
    s += __shfl_xor(s, 1); s += __shfl_xor(s, 2); s += __shfl_xor(s, 4);
    float mu = s * (1.f / 64.f);
    float v = 0.f;
#pragma unroll
    for (int k = 0; k < 8; k++) { float d = o[k] - mu; v += d * d; }
    v += __shfl_xor(v, 1); v += __shfl_xor(v, 2); v += __shfl_xor(v, 4);
    v *= (1.f / 64.f);
    float rstd = rsqrtf(v + 1e-5f);
    if (live && hlf == 0) {
        float res[8];
#pragma unroll
        for (int k = 0; k < 8; k++)
            res[k] = (o[k] - mu) * rstd * gamma[i * 8 + k] + beta[i * 8 + k];
        float4* op = (float4*)(out + (size_t)node * 64 + i * 8);
        op[0] = make_float4(res[0], res[1], res[2], res[3]);
        op[1] = make_float4(res[4], res[5], res[6], res[7]);
    }
}

extern "C" void kernel_launch(void* const* d_in, const int* in_sizes, int n_in,
                              void* d_out, int out_size, void* d_ws, size_t ws_size,
                              hipStream_t stream) {
    const float* x        = (const float*)d_in[0];
    const int*   ei       = (const int*)  d_in[1];
    const int*   type_ids = (const int*)  d_in[2];
    const float* type_emb = (const float*)d_in[3];
    const float* W1       = (const float*)d_in[4];
    const float* a_src1   = (const float*)d_in[5];
    const float* a_dst1   = (const float*)d_in[6];
    const float* b1       = (const float*)d_in[7];
    const float* W2       = (const float*)d_in[8];
    const float* a_src2   = (const float*)d_in[9];
    const float* a_dst2   = (const float*)d_in[10];
    const float* b2       = (const float*)d_in[11];
    const float* gamma    = (const float*)d_in[12];
    const float* beta     = (const float*)d_in[13];

    int N = in_sizes[0] / 5;
    int E = in_sizes[1] / 2;
    int NBKT = (N + BKT_NODES - 1) >> BKT_SHIFT;

    // Workspace: pk (16 MB, dead after k_build) overlaid on h2h/h3h (25.6 MB).
    char* base = (char*)d_ws;
    size_t off = 0;
    auto carve = [&](size_t bytes) { void* p = base + off; off += (bytes + 255) & ~(size_t)255; return p; };
    __half2* h1h = (__half2*)carve((size_t)N * 64 * sizeof(__half));
    size_t pk_bytes = (size_t)NBKT * BKT_CAP * sizeof(unsigned int);
    size_t h23_bytes = 2 * (size_t)N * 64 * sizeof(__half);
    char* uni = (char*)carve(pk_bytes > h23_bytes ? pk_bytes : h23_bytes);
    _Float16* h2h = (_Float16*)uni;
    _Float16* h3h = (_Float16*)(uni + (size_t)N * 64 * sizeof(__half));
    unsigned int* pk = (unsigned int*)uni;
    float* als1  = (float*)carve((size_t)N * 2 * sizeof(float));
    float* ald1  = (float*)carve((size_t)N * 2 * sizeof(float));
    float* als2  = (float*)carve((size_t)N * sizeof(float));
    float* ald2  = (float*)carve((size_t)N * sizeof(float));
    int*   rs    = (int*)carve((size_t)N * sizeof(int));
    int*   cur   = (int*)carve((size_t)N * sizeof(int));
    int*   bcnt  = (int*)carve(1024 * sizeof(int));
    int*   bbase = (int*)carve(1024 * sizeof(int));
    int*   ssrc  = (int*)carve((size_t)E * sizeof(int) + 256);

    dim3 tb(256);
    dim3 tb512(512);

    k_node1<<<dim3((N + 3) / 4), tb, 0, stream>>>(x, type_ids, type_emb, W1, a_src1, a_dst1,
                                                  h1h, als1, ald1, N);

    hipMemsetAsync(bcnt, 0, NBKT * sizeof(int), stream);
    k_bucketA<<<dim3((E + CHUNK - 1) / CHUNK), tb512, 0, stream>>>(ei, pk, bcnt, E, NBKT);
    k_scanb<<<dim3(1), tb512, 0, stream>>>(bcnt, bbase, NBKT);
    k_build<<<dim3(NBKT), tb512, 0, stream>>>(pk, bcnt, bbase, rs, cur, ssrc, N);

    dim3 ng((N + 15) / 16);
    k_gather1<<<ng, tb, 0, stream>>>(rs, cur, ssrc, (const float4*)h1h, als1, ald1, b1,
                                     (float4*)h2h, N);
    k_node2m<<<dim3((N + 63) / 64), tb, 0, stream>>>(h2h, W2, a_src2, a_dst2,
                                                     h3h, als2, ald2, N);
    k_gather2<<<ng, tb, 0, stream>>>(rs, cur, ssrc, (const float4*)h3h, als2, ald2, b2,
                                     gamma, beta, (float*)d_out, N);
}